// Round 1
// baseline (156.132 us; speedup 1.0000x reference)
//
#include <hip/hip_runtime.h>
#include <hip/hip_bf16.h>
#include <stdint.h>

#define NFREQ 256
#define NB 16
#define NT 4096
#define LOUT 1048832          // (4096+1)*256
#define SPAD_FRAMES 4098      // zero | t=0..4095 | zero
#define SPAD_PER_B (SPAD_FRAMES * NFREQ)

typedef __bf16 bf16;
typedef __bf16 bf16x8 __attribute__((ext_vector_type(8)));
typedef float floatx4 __attribute__((ext_vector_type(4)));

__device__ inline bf16 f2bf(float x) {
    union { float f; uint32_t u; } v; v.f = x;
    uint32_t r = (v.u + 0x7fffu + ((v.u >> 16) & 1u)) >> 16;
    union { uint16_t u; bf16 b; } o; o.u = (uint16_t)r;
    return o.b;
}

// Pass 1: spec [16][256][4096] fp32 -> Spad [16][4098][256] bf16 (transposed, +1 frame offset)
__global__ __launch_bounds__(256) void transpose_cvt(const float* __restrict__ spec,
                                                     bf16* __restrict__ spad) {
    __shared__ bf16 tile[64][72];   // [t][f], padded row 144B (16B aligned)
    int b  = blockIdx.z;
    int f0 = blockIdx.y * 64;
    int t0 = blockIdx.x * 64;
    int tid = threadIdx.x;

    int fl = tid >> 2, tq = tid & 3;
    const float* src = spec + ((size_t)b * NFREQ + (f0 + fl)) * NT + t0 + tq * 16;
    for (int i = 0; i < 4; ++i) {
        float4 v = reinterpret_cast<const float4*>(src)[i];
        int tl = tq * 16 + i * 4;
        tile[tl + 0][fl] = f2bf(v.x);
        tile[tl + 1][fl] = f2bf(v.y);
        tile[tl + 2][fl] = f2bf(v.z);
        tile[tl + 3][fl] = f2bf(v.w);
    }
    __syncthreads();
    int tl = tid >> 2, fq = tid & 3;
    bf16* dst = spad + ((size_t)b * SPAD_FRAMES + (1 + t0 + tl)) * NFREQ + f0 + fq * 16;
    const uint4* lsrc = reinterpret_cast<const uint4*>(&tile[tl][fq * 16]);
    reinterpret_cast<uint4*>(dst)[0] = lsrc[0];
    reinterpret_cast<uint4*>(dst)[1] = lsrc[1];
}

// Pass 2: Kb[r][f'] = (f'<256 ? K[r+256][f'] : K[r][f'-256]) / 128, bf16; + zero pad frames
__global__ __launch_bounds__(256) void build_kb(const float* __restrict__ ker,
                                                bf16* __restrict__ kb,
                                                bf16* __restrict__ spad) {
    int blk = blockIdx.x;
    int tid = threadIdx.x;
    if (blk < 256) {
        int base = blk * 512 + tid;
        for (int h = 0; h < 2; ++h) {
            int idx = base + h * 256;
            int r = idx >> 9, f = idx & 511;
            float v = (f < 256) ? ker[(r + 256) * 256 + f] : ker[r * 256 + (f - 256)];
            kb[idx] = f2bf(v * 0.0078125f);
        }
    } else {
        int b = blk - 256;
        size_t base = (size_t)b * SPAD_PER_B;
        spad[base + tid] = f2bf(0.0f);                          // frame 0 (t=-1)
        spad[base + (size_t)4097 * NFREQ + tid] = f2bf(0.0f);   // frame 4097 (t=4096)
    }
}

__device__ inline void load_lds16(const bf16* g, bf16* l) {
    __builtin_amdgcn_global_load_lds((__attribute__((address_space(1))) void*)g,
                                     (__attribute__((address_space(3))) void*)l,
                                     16, 0, 0);
}

// Pass 3: GEMM  out[(b,j)][r] = sum_{f'=0}^{511} A[(b,j)][f'] * Kb[r][f']
// A row (b,j) = &Spad[b][j*256], 512 contiguous bf16 (overlapping rows).
__global__ __launch_bounds__(256) void imdct_gemm(const bf16* __restrict__ spad,
                                                  const bf16* __restrict__ kb,
                                                  float* __restrict__ out) {
    __shared__ bf16 As[128 * 32];   // [m][k], rows of 64B, unpadded (global_load_lds layout)
    __shared__ bf16 Bs[128 * 32];   // [n][k]

    int jt = blockIdx.x;            // 0..32  (M tiles per batch; M=4097)
    int nt = blockIdx.y;            // 0..1
    int b  = blockIdx.z;
    int tid  = threadIdx.x;
    int lane = tid & 63;
    int w    = tid >> 6;            // wave id 0..3
    int wm = w >> 1, wn = w & 1;    // 2x2 wave grid, each wave 64x64
    int j0 = jt * 128;
    int n0 = nt * 128;

    const bf16* Ab = spad + (size_t)b * SPAD_PER_B;

    floatx4 acc[4][4] = {};

    int chunk = lane & 3;           // 16B chunk within a 64B row
    int rlane = lane >> 2;          // row within a 16-row staging call
    int row = lane & 15, q = lane >> 4;

    for (int kk = 0; kk < 512; kk += 32) {
        // stage A-tile: 128 rows x 32 k (bf16) = 8KB; wave w -> rows w*32..w*32+31
        for (int c = 0; c < 2; ++c) {
            int m = w * 32 + c * 16 + rlane;
            int j = j0 + m; if (j > 4096) j = 4096;   // clamp OOB tail rows (discarded)
            const bf16* g = Ab + (size_t)j * 256 + kk + chunk * 8;
            load_lds16(g, As + (w * 32 + c * 16) * 32);
        }
        // stage B-tile
        for (int c = 0; c < 2; ++c) {
            int n = w * 32 + c * 16 + rlane;
            const bf16* g = kb + (size_t)(n0 + n) * 512 + kk + chunk * 8;
            load_lds16(g, Bs + (w * 32 + c * 16) * 32);
        }
        __syncthreads();

        bf16x8 af[4], bf_[4];
        for (int i = 0; i < 4; ++i)
            af[i] = *reinterpret_cast<const bf16x8*>(As + (wm * 64 + i * 16 + row) * 32 + q * 8);
        for (int jn = 0; jn < 4; ++jn)
            bf_[jn] = *reinterpret_cast<const bf16x8*>(Bs + (wn * 64 + jn * 16 + row) * 32 + q * 8);

        for (int i = 0; i < 4; ++i)
            for (int jn = 0; jn < 4; ++jn)
                acc[i][jn] = __builtin_amdgcn_mfma_f32_16x16x32_bf16(af[i], bf_[jn], acc[i][jn], 0, 0, 0);

        __syncthreads();
    }

    // epilogue: C/D layout col=lane&15, row=(lane>>4)*4+reg
    for (int i = 0; i < 4; ++i) {
        int jbase = j0 + wm * 64 + i * 16 + q * 4;
        for (int jn = 0; jn < 4; ++jn) {
            int col = n0 + wn * 64 + jn * 16 + row;
            for (int e = 0; e < 4; ++e) {
                int j = jbase + e;
                if (j <= 4096)
                    out[(size_t)b * LOUT + (size_t)j * 256 + col] = acc[i][jn][e];
            }
        }
    }
}

extern "C" void kernel_launch(void* const* d_in, const int* in_sizes, int n_in,
                              void* d_out, int out_size, void* d_ws, size_t ws_size,
                              hipStream_t stream) {
    const float* spec = (const float*)d_in[0];   // [16][1][256][4096]
    const float* ker  = (const float*)d_in[1];   // [512][256]
    float* out = (float*)d_out;                  // [16][1048832]

    bf16* spad = (bf16*)d_ws;                              // 16*4098*256 bf16 = 32.0 MiB
    bf16* kb   = spad + (size_t)NB * SPAD_PER_B;           // 256*512 bf16 = 256 KiB

    transpose_cvt<<<dim3(NT / 64, NFREQ / 64, NB), 256, 0, stream>>>(spec, spad);
    build_kb<<<272, 256, 0, stream>>>(ker, kb, spad);
    imdct_gemm<<<dim3(33, 2, NB), 256, 0, stream>>>(spad, kb, out);
}

// Round 2
// 149.270 us; speedup vs baseline: 1.0460x; 1.0460x over previous
//
#include <hip/hip_runtime.h>
#include <stdint.h>

#define NFREQ 256
#define NB 16
#define NT 4096
#define LOUT 1048832          // (4096+1)*256
#define BK 64
#define AROW_U32 36           // A-tile row = 72 bf16 = 36 u32 (144 B, 16B-aligned, stride%32dw==4 -> conflict-free frag reads)
#define BGRP_B 1040           // B-tile: 8 rows x 128B + 16B pad per group -> conflict-free frag reads

typedef __bf16 bf16;
typedef __bf16 bf16x8 __attribute__((ext_vector_type(8)));
typedef float floatx4 __attribute__((ext_vector_type(4)));

__device__ inline uint32_t f_as_u(float x) { union { float f; uint32_t u; } v; v.f = x; return v.u; }

// Kb[r][f'] = (f'<256 ? K[r+256][f'] : K[r][f'-256]) / 128, bf16 RNE. 131072 elements.
__global__ __launch_bounds__(256) void build_kb(const float* __restrict__ ker,
                                                bf16* __restrict__ kb) {
    int idx = blockIdx.x * 256 + threadIdx.x;
    int r = idx >> 9, f = idx & 511;
    float v = (f < 256) ? ker[(r + 256) * 256 + f] : ker[r * 256 + (f - 256)];
    uint32_t u = f_as_u(v * 0.0078125f);
    uint32_t rr = (u + 0x7fffu + ((u >> 16) & 1u)) >> 16;
    union { uint16_t u; bf16 b; } o; o.u = (uint16_t)rr;
    kb[idx] = o.b;
}

__device__ inline void load_lds16(const bf16* g, void* l) {
    __builtin_amdgcn_global_load_lds((const __attribute__((address_space(1))) uint32_t*)g,
                                     (__attribute__((address_space(3))) uint32_t*)l,
                                     16, 0, 0);
}

// Fused GEMM: out[b][j*256+r] = sum_{f'=0}^{511} Avirt[j][f'] * Kb[r][f']
//   Avirt[j][f'] = spec[b][f'&255][ j - 1 + (f'>=256) ]   (0 outside t-range)
// Block tile: 128 j x 256 r (full N), K=512 in 8 chunks of 64.
// A staged with fused fp32->bf16 transpose (pair-packed u32 LDS writes, 2-way banks = free).
// B staged via global_load_lds width 16.
__global__ __launch_bounds__(256, 2) void imdct_gemm(const float* __restrict__ spec,
                                                     const bf16* __restrict__ kb,
                                                     float* __restrict__ out) {
    __shared__ uint32_t As[128 * AROW_U32];      // 18432 B, [j][k-pair]
    __shared__ uint8_t  Bs[32 * BGRP_B];         // 33280 B, [n-group][n&7][k]

    const int jt = blockIdx.x;                   // 0..32, tile of 128 j
    const int b  = blockIdx.y;                   // 0..15
    const int tid = threadIdx.x;
    const int lane = tid & 63;
    const int w = tid >> 6;                      // wave 0..3
    const int wm = w >> 1, wn = w & 1;           // 2x2 wave grid, wave tile 64j x 128r
    const int j0 = jt * 128;

    // A staging assignment: pair p of f-rows, chunk c of 4 t-values
    const int q2 = tid & 3;
    const int p  = (tid >> 2) & 31;
    const int h  = tid >> 7;

    const int row = lane & 15, q = lane >> 4;

    const float* specb = spec + (size_t)b * NFREQ * NT;

    floatx4 acc[4][8] = {};

    for (int kki = 0; kki < 8; ++kki) {
        const int kk = kki * BK;
        const int fbase = kk & 255;
        const int tbase = j0 - (kk < 256 ? 1 : 0);
        const bool edge = (tbase < 0) | (tbase > NT - 128);
        const float* r0 = specb + (size_t)(fbase + 2 * p) * NT;
        const float* r1 = r0 + NT;

        for (int i = 0; i < 4; ++i) {
            const int c = q2 + 16 * h + 4 * i;   // t-chunk 0..31
            const int t0 = tbase + c * 4;
            float v0[4], v1[4];
            if (!edge) {
                float4 a4 = *reinterpret_cast<const float4*>(r0 + t0);
                float4 b4 = *reinterpret_cast<const float4*>(r1 + t0);
                v0[0] = a4.x; v0[1] = a4.y; v0[2] = a4.z; v0[3] = a4.w;
                v1[0] = b4.x; v1[1] = b4.y; v1[2] = b4.z; v1[3] = b4.w;
            } else {
                for (int e = 0; e < 4; ++e) {
                    int t = t0 + e;
                    bool ok = (unsigned)t < (unsigned)NT;
                    v0[e] = ok ? r0[t] : 0.0f;
                    v1[e] = ok ? r1[t] : 0.0f;
                }
            }
            for (int e = 0; e < 4; ++e) {
                // pack bf16(v0) | bf16(v1)<<16, round-half-up
                uint32_t pk = ((f_as_u(v0[e]) + 0x8000u) >> 16) |
                              ((f_as_u(v1[e]) + 0x8000u) & 0xffff0000u);
                As[(c * 4 + e) * AROW_U32 + p] = pk;   // j = c*4+e, k-pair = p
            }
        }

        // B staging: 32 KB, 8 wave-calls per wave (each 1 KB = 8 rows of 128B)
        for (int g = 0; g < 8; ++g) {
            int grp = w * 8 + g;
            const bf16* gsrc = kb + (size_t)(grp * 8 + (lane >> 3)) * 512 + kk + (lane & 7) * 8;
            load_lds16(gsrc, Bs + grp * BGRP_B);
        }
        __syncthreads();

        for (int ks = 0; ks < 2; ++ks) {
            bf16x8 af[4], bfr[8];
            for (int i = 0; i < 4; ++i)
                af[i] = *reinterpret_cast<const bf16x8*>(
                    (const uint8_t*)As + (wm * 64 + i * 16 + row) * 144 + ks * 64 + q * 16);
            for (int jn = 0; jn < 8; ++jn) {
                int n = wn * 128 + jn * 16 + row;
                bfr[jn] = *reinterpret_cast<const bf16x8*>(
                    Bs + (n >> 3) * BGRP_B + (n & 7) * 128 + ks * 64 + q * 16);
            }
            for (int i = 0; i < 4; ++i)
                for (int jn = 0; jn < 8; ++jn)
                    acc[i][jn] = __builtin_amdgcn_mfma_f32_16x16x32_bf16(af[i], bfr[jn], acc[i][jn], 0, 0, 0);
        }
        __syncthreads();
    }

    // epilogue: C/D layout col=lane&15, row=(lane>>4)*4+e
    for (int i = 0; i < 4; ++i) {
        int jb = j0 + wm * 64 + i * 16 + q * 4;
        for (int e = 0; e < 4; ++e) {
            int j = jb + e;
            if (j <= 4096) {
                float* orow = out + (size_t)b * LOUT + (size_t)j * 256;
                for (int jn = 0; jn < 8; ++jn)
                    orow[wn * 128 + jn * 16 + row] = acc[i][jn][e];
            }
        }
    }
}

extern "C" void kernel_launch(void* const* d_in, const int* in_sizes, int n_in,
                              void* d_out, int out_size, void* d_ws, size_t ws_size,
                              hipStream_t stream) {
    const float* spec = (const float*)d_in[0];   // [16][1][256][4096] fp32
    const float* ker  = (const float*)d_in[1];   // [512][256] fp32
    float* out = (float*)d_out;                  // [16][1048832] fp32

    bf16* kb = (bf16*)d_ws;                      // 256 KB

    build_kb<<<512, 256, 0, stream>>>(ker, kb);
    imdct_gemm<<<dim3(33, NB), 256, 0, stream>>>(spec, kb, out);
}

// Round 3
// 145.557 us; speedup vs baseline: 1.0727x; 1.0255x over previous
//
#include <hip/hip_runtime.h>
#include <stdint.h>

#define NFREQ 256
#define NB 16
#define NT 4096
#define LOUT 1048832          // (4096+1)*256
#define TROWS 65              // t = j0-1 .. j0+63
#define TROW 132              // u32 per T row: 128 payload + 4 pad -> 528B row, 16B-aligned, stride%32dw==4
#define BGRP 1088             // byte stride per 8-row B group: 1024 payload + 64 pad -> 272dw %32 == 16

typedef __bf16 bf16;
typedef __bf16 bf16x8 __attribute__((ext_vector_type(8)));
typedef float floatx4 __attribute__((ext_vector_type(4)));

__device__ inline uint32_t f_as_u(float x) { union { float f; uint32_t u; } v; v.f = x; return v.u; }
__device__ inline uint32_t bf16r(float x) {     // RNE bf16 bits in low 16
    uint32_t u = f_as_u(x);
    return (u + 0x7fffu + ((u >> 16) & 1u)) >> 16;
}

// Kb[r][f'] = (f'<256 ? K[r+256][f'] : K[r][f'-256]) / 128, bf16 RNE. 131072 elements.
__global__ __launch_bounds__(256) void build_kb(const float* __restrict__ ker,
                                                bf16* __restrict__ kb) {
    int idx = blockIdx.x * 256 + threadIdx.x;
    int r = idx >> 9, f = idx & 511;
    float v = (f < 256) ? ker[(r + 256) * 256 + f] : ker[r * 256 + (f - 256)];
    uint32_t rr = bf16r(v * 0.0078125f);
    union { uint16_t u; bf16 b; } o; o.u = (uint16_t)rr;
    kb[idx] = o.b;
}

__device__ inline void load_lds16(const bf16* g, void* l) {
    __builtin_amdgcn_global_load_lds((const __attribute__((address_space(1))) uint32_t*)g,
                                     (__attribute__((address_space(3))) uint32_t*)l,
                                     16, 0, 0);
}

// out[b][j*256+r] = sum_{f'<512} Avirt[j][f'] * Kb[r][f'],  Avirt[j][f'] = spec[b][f'&255][j-1+(f'>=256)]
// Block: 64 j x 256 r. Persistent LDS T[65][256]bf16 staged once (both K-halves read same rows).
// K-loop: async-stage B chunk (L2-resident kb) -> barrier -> frags+MFMA -> barrier.
__global__ __launch_bounds__(256, 2) void imdct_gemm(const float* __restrict__ spec,
                                                     const bf16* __restrict__ kb,
                                                     float* __restrict__ out) {
    __shared__ uint32_t Tt[TROWS * TROW];    // 34320 B
    __shared__ uint8_t  Bs[32 * BGRP];       // 34816 B

    const int jt = blockIdx.x;               // 0..64
    const int b  = blockIdx.y;
    const int tid = threadIdx.x, lane = tid & 63, w = tid >> 6;
    const int j0 = jt * 64;
    const float* sb = spec + (size_t)b * NFREQ * NT;

    // ---- stage T: T[t_local][f] bf16, t = j0-1+t_local, rows 0..64 ----
    {
        const int lpar = lane & 1, lt = lane >> 1;
        const int fpw = w * 32;              // wave's f-pair base
        for (int rb = 0; rb < 4; ++rb) {
            float v[16];
            #pragma unroll
            for (int i = 0; i < 16; ++i) {   // batch loads: independent, coalesced 128B segments
                int r = rb * 16 + i;
                int tc = r >> 5, fpi = r & 31;
                int f = (fpw + fpi) * 2 + lpar;
                int t = j0 - 1 + tc * 32 + lt;
                v[i] = ((unsigned)t < (unsigned)NT) ? sb[(size_t)f * NT + t] : 0.0f;
            }
            #pragma unroll
            for (int i = 0; i < 16; i += 2) {
                int r = rb * 16 + i;
                int tc = r >> 5, fpi = r & 31;
                int tl = tc * 32 + lt;
                uint32_t h0 = bf16r(v[i]);     uint32_t o0 = (uint32_t)__shfl_xor((int)h0, 1);
                uint32_t h1 = bf16r(v[i + 1]); uint32_t o1 = (uint32_t)__shfl_xor((int)h1, 1);
                if (lpar == 0) {
                    uint2 pk; pk.x = (h0 & 0xffffu) | (o0 << 16); pk.y = (h1 & 0xffffu) | (o1 << 16);
                    *reinterpret_cast<uint2*>(&Tt[tl * TROW + fpw + fpi]) = pk;
                }
            }
        }
        // row 64 (t = j0+63): scattered single-dword round
        int f = w * 64 + lane;
        int t = j0 + 63;
        float v = ((unsigned)t < (unsigned)NT) ? sb[(size_t)f * NT + t] : 0.0f;
        uint32_t h = bf16r(v); uint32_t o = (uint32_t)__shfl_xor((int)h, 1);
        if (lpar == 0) Tt[64 * TROW + w * 32 + lt] = (h & 0xffffu) | (o << 16);
    }

    const int row16 = lane & 15, q = lane >> 4;
    floatx4 acc[4][4] = {};
    const uint8_t* Tb = reinterpret_cast<const uint8_t*>(Tt);

    for (int kki = 0; kki < 8; ++kki) {
        // stage B chunk: 256 n x 64 k bf16 = 32KB, async
        #pragma unroll
        for (int g8 = 0; g8 < 8; ++g8) {
            int g = w * 8 + g8;
            const bf16* gsrc = kb + (size_t)(g * 8 + (lane >> 3)) * 512 + kki * 64 + (lane & 7) * 8;
            load_lds16(gsrc, Bs + g * BGRP);
        }
        __syncthreads();   // also publishes T on kki==0

        const int toff = (kki >= 4) ? 1 : 0;
        const int kbyte = (kki & 3) * 128;
        #pragma unroll
        for (int ks = 0; ks < 2; ++ks) {
            bf16x8 af[4], bfr[4];
            #pragma unroll
            for (int i = 0; i < 4; ++i)
                af[i] = *reinterpret_cast<const bf16x8*>(
                    Tb + (size_t)(i * 16 + row16 + toff) * 528 + kbyte + ks * 64 + q * 16);
            #pragma unroll
            for (int jn = 0; jn < 4; ++jn) {
                int n = w * 64 + jn * 16 + row16;
                bfr[jn] = *reinterpret_cast<const bf16x8*>(
                    Bs + (n >> 3) * BGRP + (n & 7) * 128 + ks * 64 + q * 16);
            }
            #pragma unroll
            for (int i = 0; i < 4; ++i)
                #pragma unroll
                for (int jn = 0; jn < 4; ++jn)
                    acc[i][jn] = __builtin_amdgcn_mfma_f32_16x16x32_bf16(af[i], bfr[jn], acc[i][jn], 0, 0, 0);
        }
        __syncthreads();
    }

    // epilogue: C/D layout col=lane&15 (n), row=q*4+e (j within 16)
    #pragma unroll
    for (int i = 0; i < 4; ++i) {
        #pragma unroll
        for (int e = 0; e < 4; ++e) {
            int j = j0 + i * 16 + q * 4 + e;
            if (j <= 4096) {
                float* orow = out + (size_t)b * LOUT + (size_t)j * 256 + w * 64;
                #pragma unroll
                for (int jn = 0; jn < 4; ++jn)
                    orow[jn * 16 + row16] = acc[i][jn][e];
            }
        }
    }
}

extern "C" void kernel_launch(void* const* d_in, const int* in_sizes, int n_in,
                              void* d_out, int out_size, void* d_ws, size_t ws_size,
                              hipStream_t stream) {
    const float* spec = (const float*)d_in[0];   // [16][1][256][4096] fp32
    const float* ker  = (const float*)d_in[1];   // [512][256] fp32
    float* out = (float*)d_out;                  // [16][1048832] fp32

    bf16* kb = (bf16*)d_ws;                      // 256 KB scratch

    build_kb<<<512, 256, 0, stream>>>(ker, kb);
    imdct_gemm<<<dim3(65, NB), 256, 0, stream>>>(spec, kb, out);
}

// Round 4
// 142.780 us; speedup vs baseline: 1.0935x; 1.0194x over previous
//
#include <hip/hip_runtime.h>
#include <stdint.h>

#define NFREQ 256
#define NB 16
#define NT 4096
#define LOUT 1048832          // (4096+1)*256
#define TROWS 65              // t = j0-1 .. j0+63
#define TROW 132              // u32 per T row: 128 payload + 4 pad (528 B, 16B-aligned)

typedef __bf16 bf16;
typedef __bf16 bf16x8 __attribute__((ext_vector_type(8)));
typedef float floatx4 __attribute__((ext_vector_type(4)));

__device__ inline uint32_t f_as_u(float x) { union { float f; uint32_t u; } v; v.f = x; return v.u; }
__device__ inline uint32_t bf16r(float x) {     // RNE bf16 bits in low 16
    uint32_t u = f_as_u(x);
    return (u + 0x7fffu + ((u >> 16) & 1u)) >> 16;
}

// kbF frag-major: kbF[k'/32][n][k'%32] = Kb[n][k'],
//   Kb[n][f'] = (f'<256 ? K[n+256][f'] : K[n][f'-256]) / 128  (bf16 RNE)
// One wave's B-frag load (16 n-rows x 32 k) is then 1KB fully contiguous.
__global__ __launch_bounds__(256) void build_kb(const float* __restrict__ ker,
                                                bf16* __restrict__ kbF) {
    int idx = blockIdx.x * 256 + threadIdx.x;   // 131072 total
    int n = idx >> 9, f = idx & 511;
    float v = (f < 256) ? ker[(n + 256) * 256 + f] : ker[n * 256 + (f - 256)];
    uint32_t rr = bf16r(v * 0.0078125f);
    union { uint16_t u; bf16 b; } o; o.u = (uint16_t)rr;
    kbF[((size_t)(f >> 5) * 256 + n) * 32 + (f & 31)] = o.b;
}

// out[b][j*256+n] = sum_{f'<512} Avirt[j][f'] * Kb[n][f'],
//   Avirt[j][f'] = spec[b][f'&255][j-1+(f'>=256)]   (0 outside t-range)
// Block: 64 j x 256 n. LDS holds only T[65][256] bf16 (staged once, ONE barrier).
// B-frags stream global->VGPR from frag-major kbF (L2-hot, no barriers).
__global__ __launch_bounds__(256, 4) void imdct_gemm(const float* __restrict__ spec,
                                                     const bf16* __restrict__ kbF,
                                                     float* __restrict__ out) {
    __shared__ uint32_t Tt[TROWS * TROW];    // 34320 B -> 4 blocks/CU

    const int jt = blockIdx.x;               // 0..64
    const int b  = blockIdx.y;
    const int tid = threadIdx.x, lane = tid & 63, w = tid >> 6;
    const int j0 = jt * 64;
    const float* sb = spec + (size_t)b * NFREQ * NT;

    // ---- stage T: T[t_local][f] bf16, t = j0-1+t_local, rows 0..64 ----
    {
        const int lpar = lane & 1, lt = lane >> 1;
        const int fpw = w * 32;              // wave's f-pair base
        for (int rb = 0; rb < 4; ++rb) {
            float v[16];
            #pragma unroll
            for (int i = 0; i < 16; ++i) {   // independent loads, 128B segments
                int r = rb * 16 + i;
                int tc = r >> 5, fpi = r & 31;
                int f = (fpw + fpi) * 2 + lpar;
                int t = j0 - 1 + tc * 32 + lt;
                v[i] = ((unsigned)t < (unsigned)NT) ? sb[(size_t)f * NT + t] : 0.0f;
            }
            #pragma unroll
            for (int i = 0; i < 16; i += 2) {
                int r = rb * 16 + i;
                int tc = r >> 5, fpi = r & 31;
                int tl = tc * 32 + lt;
                uint32_t h0 = bf16r(v[i]);     uint32_t o0 = (uint32_t)__shfl_xor((int)h0, 1);
                uint32_t h1 = bf16r(v[i + 1]); uint32_t o1 = (uint32_t)__shfl_xor((int)h1, 1);
                if (lpar == 0) {
                    uint2 pk; pk.x = (h0 & 0xffffu) | (o0 << 16); pk.y = (h1 & 0xffffu) | (o1 << 16);
                    *reinterpret_cast<uint2*>(&Tt[tl * TROW + fpw + fpi]) = pk;
                }
            }
        }
        // row 64 (t = j0+63)
        int f = w * 64 + lane;
        int t = j0 + 63;
        float v = ((unsigned)t < (unsigned)NT) ? sb[(size_t)f * NT + t] : 0.0f;
        uint32_t h = bf16r(v); uint32_t o = (uint32_t)__shfl_xor((int)h, 1);
        if (lpar == 0) Tt[64 * TROW + w * 32 + lt] = (h & 0xffffu) | (o << 16);
    }
    __syncthreads();                         // the ONLY barrier

    const int row16 = lane & 15, q = lane >> 4;
    floatx4 acc[4][4] = {};
    const uint8_t* Tb = reinterpret_cast<const uint8_t*>(Tt);
    const bf16* kbw = kbF + (size_t)w * 64 * 32;   // wave's n-slice base

    for (int kki = 0; kki < 8; ++kki) {
        const int toff = (kki >= 4) ? 1 : 0;
        const int kbyte = (kki & 3) * 128;
        #pragma unroll
        for (int ks = 0; ks < 2; ++ks) {
            const int kchunk = kki * 2 + ks;
            bf16x8 af[4], bfr[4];
            #pragma unroll
            for (int i = 0; i < 4; ++i)
                af[i] = *reinterpret_cast<const bf16x8*>(
                    Tb + (size_t)(i * 16 + row16 + toff) * 528 + kbyte + ks * 64 + q * 16);
            #pragma unroll
            for (int jn = 0; jn < 4; ++jn)
                bfr[jn] = *reinterpret_cast<const bf16x8*>(
                    kbw + (size_t)kchunk * 8192 + (jn * 16 + row16) * 32 + q * 8);
            #pragma unroll
            for (int i = 0; i < 4; ++i)
                #pragma unroll
                for (int jn = 0; jn < 4; ++jn)
                    acc[i][jn] = __builtin_amdgcn_mfma_f32_16x16x32_bf16(af[i], bfr[jn], acc[i][jn], 0, 0, 0);
        }
    }

    // epilogue: C/D layout col=lane&15 (n), row=q*4+e (j within 16)
    #pragma unroll
    for (int i = 0; i < 4; ++i) {
        #pragma unroll
        for (int e = 0; e < 4; ++e) {
            int j = j0 + i * 16 + q * 4 + e;
            if (j <= 4096) {
                float* orow = out + (size_t)b * LOUT + (size_t)j * 256 + w * 64;
                #pragma unroll
                for (int jn = 0; jn < 4; ++jn)
                    orow[jn * 16 + row16] = acc[i][jn][e];
            }
        }
    }
}

extern "C" void kernel_launch(void* const* d_in, const int* in_sizes, int n_in,
                              void* d_out, int out_size, void* d_ws, size_t ws_size,
                              hipStream_t stream) {
    const float* spec = (const float*)d_in[0];   // [16][1][256][4096] fp32
    const float* ker  = (const float*)d_in[1];   // [512][256] fp32
    float* out = (float*)d_out;                  // [16][1048832] fp32

    bf16* kbF = (bf16*)d_ws;                     // 256 KB scratch

    build_kb<<<512, 256, 0, stream>>>(ker, kbF);
    imdct_gemm<<<dim3(65, NB), 256, 0, stream>>>(spec, kbF, out);
}